// Round 18
// baseline (75.276 us; speedup 1.0000x reference)
//
#include <hip/hip_runtime.h>

constexpr int NP = 12288;   // N points
constexpr int NB = 4;       // batches
constexpr int MC = 1024;    // M context
constexpr int DM = 256;     // D
constexpr int KVD = 512;    // KV feature dim
constexpr int NH = 8;       // heads
constexpr int DH = 32;      // head dim

typedef __bf16 bf16x8 __attribute__((ext_vector_type(8)));
typedef __bf16 bf16x4 __attribute__((ext_vector_type(4)));
typedef float f32x4v __attribute__((ext_vector_type(4)));

__device__ inline bf16x8 pack8(float4 a, float4 b) {
    bf16x8 r;
    r[0] = (__bf16)a.x; r[1] = (__bf16)a.y; r[2] = (__bf16)a.z; r[3] = (__bf16)a.w;
    r[4] = (__bf16)b.x; r[5] = (__bf16)b.y; r[6] = (__bf16)b.z; r[7] = (__bf16)b.w;
    return r;
}

// Merged prep: block 0 -> starts; blocks [1,384] -> weight fp32->bf16;
// blocks [385, 385+1536) -> LN1 of F (8 rows/block, bf16 out).
__global__ __launch_bounds__(256) void k_prep(const float* __restrict__ F,
        const int* __restrict__ bidx,
        const float* __restrict__ wq, const float* __restrict__ wk,
        const float* __restrict__ wv, const float* __restrict__ wo,
        const float* __restrict__ g, const float* __restrict__ bb,
        int* __restrict__ starts,
        __bf16* wqb, __bf16* wkb, __bf16* wvb, __bf16* wob,
        __bf16* __restrict__ q_in_b) {
    const int bid = blockIdx.x, t = threadIdx.x;
    if (bid == 0) {
        if (t > NB) return;
        int lo = 0, hi = NP;
        while (lo < hi) { int mid = (lo + hi) >> 1; if (bidx[mid] < t) lo = mid + 1; else hi = mid; }
        starts[t] = lo;
        return;
    }
    if (bid <= 384) {
        size_t i = ((size_t)(bid - 1) * 256 + t) * 4;
        const float* s; __bf16* d; size_t off;
        if      (i < 65536)  { s = wq; d = wqb; off = 0; }
        else if (i < 196608) { s = wk; d = wkb; off = 65536; }
        else if (i < 327680) { s = wv; d = wvb; off = 196608; }
        else                 { s = wo; d = wob; off = 327680; }
        size_t j = i - off;
        float4 v = *(const float4*)&s[j];
        bf16x4 o; o[0] = (__bf16)v.x; o[1] = (__bf16)v.y; o[2] = (__bf16)v.z; o[3] = (__bf16)v.w;
        *(bf16x4*)&d[j] = o;
        return;
    }
    // LN1: 8 rows per block (wave handles 2 rows sequentially)
    const int w = t >> 6, l = t & 63;
#pragma unroll
    for (int rr2 = 0; rr2 < 2; ++rr2) {
        size_t row = (size_t)(bid - 385) * 8 + w * 2 + rr2;
        float4 v = *(const float4*)&F[row * DM + l * 4];
        float s = v.x + v.y + v.z + v.w;
#pragma unroll
        for (int o2 = 1; o2 < 64; o2 <<= 1) s += __shfl_xor(s, o2);
        float mu = s * (1.f / DM);
        float4 d = {v.x - mu, v.y - mu, v.z - mu, v.w - mu};
        float ss = d.x * d.x + d.y * d.y + d.z * d.z + d.w * d.w;
#pragma unroll
        for (int o2 = 1; o2 < 64; o2 <<= 1) ss += __shfl_xor(ss, o2);
        float rr = rsqrtf(ss * (1.f / DM) + 1e-5f);
        float4 gg = *(const float4*)&g[l * 4];
        float4 bv = *(const float4*)&bb[l * 4];
        bf16x4 ob4;
        ob4[0] = (__bf16)(d.x * rr * gg.x + bv.x);
        ob4[1] = (__bf16)(d.y * rr * gg.y + bv.y);
        ob4[2] = (__bf16)(d.z * rr * gg.z + bv.z);
        ob4[3] = (__bf16)(d.w * rr * gg.w + bv.w);
        *(bf16x4*)&q_in_b[row * DM + l * 4] = ob4;
    }
}

// Merged Q + K + V projections (fragment-layout K/V out).
// LPT order: KV blocks (8 k-iters) FIRST [0,512), Q blocks (4 k-iters) after.
__global__ __launch_bounds__(256) void k_qkv(const __bf16* __restrict__ Aq,
        const __bf16* __restrict__ Wq, const float* __restrict__ bq,
        const float* __restrict__ Yf,
        const __bf16* __restrict__ Wk, const float* __restrict__ bk,
        const __bf16* __restrict__ Wv, const float* __restrict__ bv,
        __bf16* __restrict__ Qo, __bf16* __restrict__ Kf,
        __bf16* __restrict__ Vf, float qscale) {
    __shared__ __bf16 As[128][68];
    __shared__ __bf16 Bs[64][68];
    const int t = threadIdx.x;
    const int w = t >> 6, l = t & 63, lg = l >> 4, ln = l & 15;
    const int wr = w >> 1, wc = w & 1;
    const int ar = t >> 3, ac8 = (t & 7) * 8;
    if ((int)blockIdx.x >= 512) {
        // ---------------- Q path ----------------
        f32x4v acc[4][2] = {};
        const int K = DM;
        const int qid = blockIdx.x - 512;
        const int col0 = (qid & 3) * 64, row0 = (qid >> 2) * 128;
        bf16x8 ra0, ra1, ra2, ra3, rb0, rb1;
#define LOADGQ(K0) \
        ra0 = *(const bf16x8*)&Aq[(size_t)(row0 + ar) * K + (K0) + ac8];        \
        ra1 = *(const bf16x8*)&Aq[(size_t)(row0 + ar + 32) * K + (K0) + ac8];   \
        ra2 = *(const bf16x8*)&Aq[(size_t)(row0 + ar + 64) * K + (K0) + ac8];   \
        ra3 = *(const bf16x8*)&Aq[(size_t)(row0 + ar + 96) * K + (K0) + ac8];   \
        rb0 = *(const bf16x8*)&Wq[(size_t)(col0 + ar) * K + (K0) + ac8];        \
        rb1 = *(const bf16x8*)&Wq[(size_t)(col0 + ar + 32) * K + (K0) + ac8];
        LOADGQ(0)
        for (int k0 = 0; k0 < K; k0 += 64) {
            __syncthreads();
            *(bf16x8*)&As[ar][ac8] = ra0;
            *(bf16x8*)&As[ar + 32][ac8] = ra1;
            *(bf16x8*)&As[ar + 64][ac8] = ra2;
            *(bf16x8*)&As[ar + 96][ac8] = ra3;
            *(bf16x8*)&Bs[ar][ac8] = rb0;
            *(bf16x8*)&Bs[ar + 32][ac8] = rb1;
            __syncthreads();
            if (k0 + 64 < K) { LOADGQ(k0 + 64) }
#pragma unroll
            for (int kk = 0; kk < 2; ++kk) {
                bf16x8 bfr[2];
#pragma unroll
                for (int ni = 0; ni < 2; ++ni) {
                    bf16x4 lo = *(const bf16x4*)&Bs[wc * 32 + ni * 16 + ln][kk * 32 + lg * 4];
                    bf16x4 hi = *(const bf16x4*)&Bs[wc * 32 + ni * 16 + ln][kk * 32 + 16 + lg * 4];
                    bfr[ni] = __builtin_shufflevector(lo, hi, 0, 1, 2, 3, 4, 5, 6, 7);
                }
#pragma unroll
                for (int mi = 0; mi < 4; ++mi) {
                    bf16x4 lo = *(const bf16x4*)&As[wr * 64 + mi * 16 + ln][kk * 32 + lg * 4];
                    bf16x4 hi = *(const bf16x4*)&As[wr * 64 + mi * 16 + ln][kk * 32 + 16 + lg * 4];
                    bf16x8 af = __builtin_shufflevector(lo, hi, 0, 1, 2, 3, 4, 5, 6, 7);
#pragma unroll
                    for (int ni = 0; ni < 2; ++ni)
                        acc[mi][ni] = __builtin_amdgcn_mfma_f32_16x16x32_bf16(bfr[ni], af, acc[mi][ni], 0, 0, 0);
                }
            }
        }
#undef LOADGQ
#pragma unroll
        for (int mi = 0; mi < 4; ++mi)
#pragma unroll
            for (int ni = 0; ni < 2; ++ni) {
                int cb = col0 + wc * 32 + ni * 16 + 4 * lg;
                float4 b4 = *(const float4*)&bq[cb];
                size_t row = row0 + wr * 64 + mi * 16 + ln;
                bf16x4 pk;
                pk[0] = (__bf16)((acc[mi][ni][0] + b4.x) * qscale);
                pk[1] = (__bf16)((acc[mi][ni][1] + b4.y) * qscale);
                pk[2] = (__bf16)((acc[mi][ni][2] + b4.z) * qscale);
                pk[3] = (__bf16)((acc[mi][ni][3] + b4.w) * qscale);
                *(bf16x4*)&Qo[row * DM + cb] = pk;
            }
    } else {
        // ---------------- K/V path (64-row tiles), blocks [0,512) ----------------
        f32x4v acc[2][2] = {};
        const int K = KVD;
        const int idx = blockIdx.x;
        const int bx = idx & 7, row0 = (idx >> 3) * 64;
        const bool vpath = bx >= 4;
        const int col0 = (bx & 3) * 64;
        const __bf16* Wm = vpath ? Wv : Wk;
        const float* bi = vpath ? bv : bk;
        float4 a0, a1, a2, a3;
        bf16x8 rb0, rb1;
#define LOADGK(K0) \
        a0 = *(const float4*)&Yf[(size_t)(row0 + ar) * K + (K0) + ac8];            \
        a1 = *(const float4*)&Yf[(size_t)(row0 + ar) * K + (K0) + ac8 + 4];        \
        a2 = *(const float4*)&Yf[(size_t)(row0 + ar + 32) * K + (K0) + ac8];       \
        a3 = *(const float4*)&Yf[(size_t)(row0 + ar + 32) * K + (K0) + ac8 + 4];   \
        rb0 = *(const bf16x8*)&Wm[(size_t)(col0 + ar) * K + (K0) + ac8];           \
        rb1 = *(const bf16x8*)&Wm[(size_t)(col0 + ar + 32) * K + (K0) + ac8];
        LOADGK(0)
        for (int k0 = 0; k0 < K; k0 += 64) {
            __syncthreads();
            *(bf16x8*)&As[ar][ac8] = pack8(a0, a1);
            *(bf16x8*)&As[ar + 32][ac8] = pack8(a2, a3);
            *(bf16x8*)&Bs[ar][ac8] = rb0;
            *(bf16x8*)&Bs[ar + 32][ac8] = rb1;
            __syncthreads();
            if (k0 + 64 < K) { LOADGK(k0 + 64) }
#pragma unroll
            for (int kk = 0; kk < 2; ++kk) {
                bf16x8 bfr[2];
#pragma unroll
                for (int ni = 0; ni < 2; ++ni) {
                    bf16x4 lo = *(const bf16x4*)&Bs[wc * 32 + ni * 16 + ln][kk * 32 + lg * 4];
                    bf16x4 hi = *(const bf16x4*)&Bs[wc * 32 + ni * 16 + ln][kk * 32 + 16 + lg * 4];
                    bfr[ni] = __builtin_shufflevector(lo, hi, 0, 1, 2, 3, 4, 5, 6, 7);
                }
#pragma unroll
                for (int mi = 0; mi < 2; ++mi) {
                    bf16x4 lo = *(const bf16x4*)&As[wr * 32 + mi * 16 + ln][kk * 32 + lg * 4];
                    bf16x4 hi = *(const bf16x4*)&As[wr * 32 + mi * 16 + ln][kk * 32 + 16 + lg * 4];
                    bf16x8 af = __builtin_shufflevector(lo, hi, 0, 1, 2, 3, 4, 5, 6, 7);
#pragma unroll
                    for (int ni = 0; ni < 2; ++ni) {
                        if (vpath)
                            acc[mi][ni] = __builtin_amdgcn_mfma_f32_16x16x32_bf16(af, bfr[ni], acc[mi][ni], 0, 0, 0);
                        else
                            acc[mi][ni] = __builtin_amdgcn_mfma_f32_16x16x32_bf16(bfr[ni], af, acc[mi][ni], 0, 0, 0);
                    }
                }
            }
        }
#undef LOADGK
        if (vpath) {
            const int h = (col0 + wc * 32) >> 5;
#pragma unroll
            for (int mi = 0; mi < 2; ++mi)
#pragma unroll
                for (int ni = 0; ni < 2; ++ni) {
                    int C = col0 + wc * 32 + ni * 16 + ln;
                    int nt = (C >> 4) & 1;
                    float bvv = bi[C];
                    int m = row0 + wr * 32 + mi * 16 + 4 * lg;
                    int b = m >> 10, mlocal = m & 1023;
                    int mhg = mlocal >> 5;
                    bf16x4 pk;
#pragma unroll
                    for (int r = 0; r < 4; ++r) pk[r] = (__bf16)(acc[mi][ni][r] + bvv);
                    *(bf16x4*)&Vf[(size_t)(((b * NH + h) * 32 + mhg) * 2 + nt) * 512 + l * 8 + mi * 4] = pk;
                }
        } else {
            const int h = (col0 + wc * 32) >> 5;
#pragma unroll
            for (int mi = 0; mi < 2; ++mi) {
                int m = row0 + wr * 32 + mi * 16 + ln;
                int b = m >> 10, mlocal = m & 1023;
                int msg = mlocal >> 4;
#pragma unroll
                for (int ni = 0; ni < 2; ++ni) {
                    int cb = col0 + wc * 32 + ni * 16 + 4 * lg;
                    float4 b4 = *(const float4*)&bi[cb];
                    bf16x4 pk;
                    pk[0] = (__bf16)(acc[mi][ni][0] + b4.x);
                    pk[1] = (__bf16)(acc[mi][ni][1] + b4.y);
                    pk[2] = (__bf16)(acc[mi][ni][2] + b4.z);
                    pk[3] = (__bf16)(acc[mi][ni][3] + b4.w);
                    *(bf16x4*)&Kf[(size_t)((b * NH + h) * 64 + msg) * 512 + l * 8 + ni * 4] = pk;
                }
            }
        }
    }
}

// Flash cross-attention: ZERO LDS/barriers, fragment-layout K/V (L2-resident),
// NO-MAX exp2 softmax, MFMA-pipe denominator. 64 q-rows per block (1 Q frag
// per wave) -> ~1536 working blocks = 6 waves/SIMD for latency hiding.
__global__ __launch_bounds__(256) void k_attn_mfma(const __bf16* __restrict__ q,
        const __bf16* __restrict__ Kf, const __bf16* __restrict__ Vf,
        const int* __restrict__ starts, __bf16* __restrict__ o) {
    const int b = blockIdx.z, h = blockIdx.y;
    const int r0 = starts[b] + blockIdx.x * 64;
    const int rend = starts[b + 1];
    if (r0 >= rend) return;
    const int nr = min(64, rend - r0);

    const int t = threadIdx.x;
    const int w = t >> 6, l = t & 63, lg = l >> 4, ln = l & 15;

    const __bf16* kfb = Kf + (size_t)(b * NH + h) * 32768;
    const __bf16* vfb = Vf + (size_t)(b * NH + h) * 32768;

    const int qr0 = min(r0 + w * 16 + ln, NP - 1);
    const __bf16* qp0 = q + (size_t)qr0 * DM + h * DH;
    bf16x8 qf0 = __builtin_shufflevector(*(const bf16x4*)(qp0 + lg * 4),
                                         *(const bf16x4*)(qp0 + 16 + lg * 4),
                                         0, 1, 2, 3, 4, 5, 6, 7);

    bf16x8 onesf;
#pragma unroll
    for (int j = 0; j < 8; ++j) onesf[j] = (__bf16)1.0f;

    f32x4v Oacc[2] = {{0.f, 0.f, 0.f, 0.f}, {0.f, 0.f, 0.f, 0.f}};
    f32x4v Lacc = {0.f, 0.f, 0.f, 0.f};

    for (int mt = 0; mt < 8; ++mt) {
        bf16x8 kfr[8];
#pragma unroll
        for (int ms = 0; ms < 8; ++ms)
            kfr[ms] = *(const bf16x8*)&kfb[(size_t)((mt * 8 + ms) * 64 + l) * 8];
        f32x4v S0[8];
        __builtin_amdgcn_s_setprio(1);
#pragma unroll
        for (int ms = 0; ms < 8; ++ms)
            S0[ms] = __builtin_amdgcn_mfma_f32_16x16x32_bf16(
                kfr[ms], qf0, (f32x4v){0.f, 0.f, 0.f, 0.f}, 0, 0, 0);
        __builtin_amdgcn_s_setprio(0);
        bf16x8 vfr[8];
#pragma unroll
        for (int i = 0; i < 8; ++i)
            vfr[i] = *(const bf16x8*)&vfb[(size_t)((mt * 8 + i) * 64 + l) * 8];
        // p = exp2(S), pack only (sums on MFMA pipe)
        bf16x8 pa0[4];
#pragma unroll
        for (int ms = 0; ms < 8; ++ms) {
            const int mh = ms >> 1, j0 = (ms & 1) * 4;
#pragma unroll
            for (int r = 0; r < 4; ++r)
                pa0[mh][j0 + r] = (__bf16)__builtin_amdgcn_exp2f(S0[ms][r]);
        }
        // PV + denominator-MFMA
        __builtin_amdgcn_s_setprio(1);
#pragma unroll
        for (int mh = 0; mh < 4; ++mh) {
#pragma unroll
            for (int nt = 0; nt < 2; ++nt)
                Oacc[nt] = __builtin_amdgcn_mfma_f32_16x16x32_bf16(pa0[mh], vfr[mh * 2 + nt], Oacc[nt], 0, 0, 0);
            Lacc = __builtin_amdgcn_mfma_f32_16x16x32_bf16(pa0[mh], onesf, Lacc, 0, 0, 0);
        }
        __builtin_amdgcn_s_setprio(0);
    }
    // epilogue: Lacc[r] == row-sum for row 4lg+r (all lanes) -- no shuffles.
#pragma unroll
    for (int r = 0; r < 4; ++r) {
        float iv = 1.0f / Lacc[r];
        int rloc = w * 16 + 4 * lg + r;
        if (rloc < nr) {
            size_t base = (size_t)(r0 + rloc) * DM + h * DH + ln;
            o[base] = (__bf16)(Oacc[0][r] * iv);
            o[base + 16] = (__bf16)(Oacc[1][r] * iv);
        }
    }
}

// Wo projection + residual + final LayerNorm, fused. Tile 32 rows x 256 cols.
__global__ __launch_bounds__(256) void k_gemmo_ln(const __bf16* __restrict__ A,
        const __bf16* __restrict__ W, const float* __restrict__ bias,
        const __bf16* __restrict__ resid, const float* __restrict__ g,
        const float* __restrict__ bb, float* __restrict__ out) {
    __shared__ __bf16 As[32][68];
    __shared__ __bf16 Bs[256][68];
    __shared__ float red[32][4][2];
    const int t = threadIdx.x;
    const int w = t >> 6, l = t & 63, lg = l >> 4, ln = l & 15;
    const int row0 = blockIdx.x * 32;
    const int ar = t >> 3, ac8 = (t & 7) * 8;
    f32x4v acc[2][4] = {};
    for (int k0 = 0; k0 < DM; k0 += 64) {
        __syncthreads();
        *(bf16x8*)&As[ar][ac8] = *(const bf16x8*)&A[(size_t)(row0 + ar) * DM + k0 + ac8];
#pragma unroll
        for (int j = 0; j < 8; ++j)
            *(bf16x8*)&Bs[ar + 32 * j][ac8] = *(const bf16x8*)&W[(size_t)(ar + 32 * j) * DM + k0 + ac8];
        __syncthreads();
#pragma unroll
        for (int kk = 0; kk < 2; ++kk) {
            bf16x8 bfr[4];
#pragma unroll
            for (int ni = 0; ni < 4; ++ni) {
                bf16x4 lo = *(const bf16x4*)&Bs[w * 64 + ni * 16 + ln][kk * 32 + lg * 4];
                bf16x4 hi = *(const bf16x4*)&Bs[w * 64 + ni * 16 + ln][kk * 32 + 16 + lg * 4];
                bfr[ni] = __builtin_shufflevector(lo, hi, 0, 1, 2, 3, 4, 5, 6, 7);
            }
#pragma unroll
            for (int mi = 0; mi < 2; ++mi) {
                bf16x4 lo = *(const bf16x4*)&As[mi * 16 + ln][kk * 32 + lg * 4];
                bf16x4 hi = *(const bf16x4*)&As[mi * 16 + ln][kk * 32 + 16 + lg * 4];
                bf16x8 af = __builtin_shufflevector(lo, hi, 0, 1, 2, 3, 4, 5, 6, 7);
#pragma unroll
                for (int ni = 0; ni < 4; ++ni)
                    acc[mi][ni] = __builtin_amdgcn_mfma_f32_16x16x32_bf16(bfr[ni], af, acc[mi][ni], 0, 0, 0);
            }
        }
    }
    float s[2] = {0.f, 0.f}, ss[2] = {0.f, 0.f};
#pragma unroll
    for (int mi = 0; mi < 2; ++mi) {
        int row = row0 + mi * 16 + ln;
#pragma unroll
        for (int ni = 0; ni < 4; ++ni) {
            int cb = w * 64 + ni * 16 + lg * 4;
            float4 b4 = *(const float4*)&bias[cb];
            bf16x4 rv = *(const bf16x4*)&resid[(size_t)row * DM + cb];
            float z0 = acc[mi][ni][0] + b4.x + (float)rv[0];
            float z1 = acc[mi][ni][1] + b4.y + (float)rv[1];
            float z2 = acc[mi][ni][2] + b4.z + (float)rv[2];
            float z3 = acc[mi][ni][3] + b4.w + (float)rv[3];
            acc[mi][ni][0] = z0; acc[mi][ni][1] = z1;
            acc[mi][ni][2] = z2; acc[mi][ni][3] = z3;
            s[mi] += (z0 + z1) + (z2 + z3);
            ss[mi] += (z0 * z0 + z1 * z1) + (z2 * z2 + z3 * z3);
        }
    }
#pragma unroll
    for (int mi = 0; mi < 2; ++mi) {
        s[mi] += __shfl_xor(s[mi], 16);  s[mi] += __shfl_xor(s[mi], 32);
        ss[mi] += __shfl_xor(ss[mi], 16); ss[mi] += __shfl_xor(ss[mi], 32);
    }
    if (l < 16) {
#pragma unroll
        for (int mi = 0; mi < 2; ++mi) {
            red[mi * 16 + ln][w][0] = s[mi];
            red[mi * 16 + ln][w][1] = ss[mi];
        }
    }
    __syncthreads();
#pragma unroll
    for (int mi = 0; mi < 2; ++mi) {
        int rloc = mi * 16 + ln;
        float su = (red[rloc][0][0] + red[rloc][1][0]) + (red[rloc][2][0] + red[rloc][3][0]);
        float sq = (red[rloc][0][1] + red[rloc][1][1]) + (red[rloc][2][1] + red[rloc][3][1]);
        float mu = su * (1.f / DM);
        float var = sq * (1.f / DM) - mu * mu;
        float rs = rsqrtf(var + 1e-5f);
        size_t row = row0 + rloc;
#pragma unroll
        for (int ni = 0; ni < 4; ++ni) {
            int cb = w * 64 + ni * 16 + lg * 4;
            float4 g4 = *(const float4*)&g[cb];
            float4 bb4 = *(const float4*)&bb[cb];
            float4 o4;
            o4.x = (acc[mi][ni][0] - mu) * rs * g4.x + bb4.x;
            o4.y = (acc[mi][ni][1] - mu) * rs * g4.y + bb4.y;
            o4.z = (acc[mi][ni][2] - mu) * rs * g4.z + bb4.z;
            o4.w = (acc[mi][ni][3] - mu) * rs * g4.w + bb4.w;
            *(float4*)&out[row * DM + cb] = o4;
        }
    }
}

extern "C" void kernel_launch(void* const* d_in, const int* in_sizes, int n_in,
                              void* d_out, int out_size, void* d_ws, size_t ws_size,
                              hipStream_t stream) {
    const float* F  = (const float*)d_in[0];
    const int* bidx = (const int*)d_in[1];
    const float* y  = (const float*)d_in[2];
    const float* Wq = (const float*)d_in[3];
    const float* bq = (const float*)d_in[4];
    const float* Wk = (const float*)d_in[5];
    const float* bk = (const float*)d_in[6];
    const float* Wv = (const float*)d_in[7];
    const float* bv = (const float*)d_in[8];
    const float* Wo = (const float*)d_in[9];
    const float* bo = (const float*)d_in[10];
    const float* lg = (const float*)d_in[11];
    const float* lb = (const float*)d_in[12];
    float* out = (float*)d_out;

    char* ws = (char*)d_ws;
    __bf16* q_in_b = (__bf16*)ws;   ws += (size_t)NP * DM * 2;
    __bf16* qb     = (__bf16*)ws;   ws += (size_t)NP * DM * 2;
    __bf16* ob     = (__bf16*)ws;   ws += (size_t)NP * DM * 2;
    __bf16* Kf     = (__bf16*)ws;   ws += (size_t)NB * MC * DM * 2;
    __bf16* Vf     = (__bf16*)ws;   ws += (size_t)NB * DM * MC * 2;
    __bf16* Wq_b   = (__bf16*)ws;   ws += (size_t)DM * DM * 2;
    __bf16* Wk_b   = (__bf16*)ws;   ws += (size_t)DM * KVD * 2;
    __bf16* Wv_b   = (__bf16*)ws;   ws += (size_t)DM * KVD * 2;
    __bf16* Wo_b   = (__bf16*)ws;   ws += (size_t)DM * DM * 2;
    int* starts    = (int*)ws;

    const float qscale = 0.17677669529663687f * 1.4426950408889634f; // 1/sqrt(32)*log2e

    k_prep<<<1 + 384 + NP / 8, 256, 0, stream>>>(F, bidx, Wq, Wk, Wv, Wo, lg, lb,
            starts, Wq_b, Wk_b, Wv_b, Wo_b, q_in_b);
    k_qkv<<<512 + 384, 256, 0, stream>>>(q_in_b, Wq_b, bq, y, Wk_b, bk, Wv_b, bv,
            qb, Kf, Vf, qscale);
    k_attn_mfma<<<dim3(NP / 64, NH, NB), 256, 0, stream>>>(qb, Kf, Vf, starts, ob);
    k_gemmo_ln<<<NP / 32, 256, 0, stream>>>(ob, Wo_b, bo, q_in_b, lg, lb, out);
}

// Round 19
// 70.266 us; speedup vs baseline: 1.0713x; 1.0713x over previous
//
#include <hip/hip_runtime.h>

constexpr int NP = 12288;   // N points
constexpr int NB = 4;       // batches
constexpr int MC = 1024;    // M context
constexpr int DM = 256;     // D
constexpr int KVD = 512;    // KV feature dim
constexpr int NH = 8;       // heads
constexpr int DH = 32;      // head dim

typedef __bf16 bf16x8 __attribute__((ext_vector_type(8)));
typedef __bf16 bf16x4 __attribute__((ext_vector_type(4)));
typedef float f32x4v __attribute__((ext_vector_type(4)));

__device__ inline bf16x8 pack8(float4 a, float4 b) {
    bf16x8 r;
    r[0] = (__bf16)a.x; r[1] = (__bf16)a.y; r[2] = (__bf16)a.z; r[3] = (__bf16)a.w;
    r[4] = (__bf16)b.x; r[5] = (__bf16)b.y; r[6] = (__bf16)b.z; r[7] = (__bf16)b.w;
    return r;
}

// Merged prep: block 0 -> starts; blocks [1,384] -> weight fp32->bf16;
// blocks [385, 385+3072) -> LN1 of F (bf16 out).
__global__ __launch_bounds__(256) void k_prep(const float* __restrict__ F,
        const int* __restrict__ bidx,
        const float* __restrict__ wq, const float* __restrict__ wk,
        const float* __restrict__ wv, const float* __restrict__ wo,
        const float* __restrict__ g, const float* __restrict__ bb,
        int* __restrict__ starts,
        __bf16* wqb, __bf16* wkb, __bf16* wvb, __bf16* wob,
        __bf16* __restrict__ q_in_b) {
    const int bid = blockIdx.x, t = threadIdx.x;
    if (bid == 0) {
        if (t > NB) return;
        int lo = 0, hi = NP;
        while (lo < hi) { int mid = (lo + hi) >> 1; if (bidx[mid] < t) lo = mid + 1; else hi = mid; }
        starts[t] = lo;
        return;
    }
    if (bid <= 384) {
        size_t i = ((size_t)(bid - 1) * 256 + t) * 4;
        const float* s; __bf16* d; size_t off;
        if      (i < 65536)  { s = wq; d = wqb; off = 0; }
        else if (i < 196608) { s = wk; d = wkb; off = 65536; }
        else if (i < 327680) { s = wv; d = wvb; off = 196608; }
        else                 { s = wo; d = wob; off = 327680; }
        size_t j = i - off;
        float4 v = *(const float4*)&s[j];
        bf16x4 o; o[0] = (__bf16)v.x; o[1] = (__bf16)v.y; o[2] = (__bf16)v.z; o[3] = (__bf16)v.w;
        *(bf16x4*)&d[j] = o;
        return;
    }
    // LN1: 4 rows per block, wave per row
    const int w = t >> 6, l = t & 63;
    size_t row = (size_t)(bid - 385) * 4 + w;
    float4 v = *(const float4*)&F[row * DM + l * 4];
    float s = v.x + v.y + v.z + v.w;
#pragma unroll
    for (int o2 = 1; o2 < 64; o2 <<= 1) s += __shfl_xor(s, o2);
    float mu = s * (1.f / DM);
    float4 d = {v.x - mu, v.y - mu, v.z - mu, v.w - mu};
    float ss = d.x * d.x + d.y * d.y + d.z * d.z + d.w * d.w;
#pragma unroll
    for (int o2 = 1; o2 < 64; o2 <<= 1) ss += __shfl_xor(ss, o2);
    float rr = rsqrtf(ss * (1.f / DM) + 1e-5f);
    float4 gg = *(const float4*)&g[l * 4];
    float4 bv = *(const float4*)&bb[l * 4];
    bf16x4 ob4;
    ob4[0] = (__bf16)(d.x * rr * gg.x + bv.x);
    ob4[1] = (__bf16)(d.y * rr * gg.y + bv.y);
    ob4[2] = (__bf16)(d.z * rr * gg.z + bv.z);
    ob4[3] = (__bf16)(d.w * rr * gg.w + bv.w);
    *(bf16x4*)&q_in_b[row * DM + l * 4] = ob4;
}

// Merged Q + K + V projections (fragment-layout K/V out).
__global__ __launch_bounds__(256) void k_qkv(const __bf16* __restrict__ Aq,
        const __bf16* __restrict__ Wq, const float* __restrict__ bq,
        const float* __restrict__ Yf,
        const __bf16* __restrict__ Wk, const float* __restrict__ bk,
        const __bf16* __restrict__ Wv, const float* __restrict__ bv,
        __bf16* __restrict__ Qo, __bf16* __restrict__ Kf,
        __bf16* __restrict__ Vf, float qscale) {
    __shared__ __bf16 As[128][68];
    __shared__ __bf16 Bs[64][68];
    const int t = threadIdx.x;
    const int w = t >> 6, l = t & 63, lg = l >> 4, ln = l & 15;
    const int wr = w >> 1, wc = w & 1;
    const int ar = t >> 3, ac8 = (t & 7) * 8;
    if ((int)blockIdx.x < 384) {
        // ---------------- Q path ----------------
        f32x4v acc[4][2] = {};
        const int K = DM;
        const int col0 = (blockIdx.x & 3) * 64, row0 = (blockIdx.x >> 2) * 128;
        bf16x8 ra0, ra1, ra2, ra3, rb0, rb1;
#define LOADGQ(K0) \
        ra0 = *(const bf16x8*)&Aq[(size_t)(row0 + ar) * K + (K0) + ac8];        \
        ra1 = *(const bf16x8*)&Aq[(size_t)(row0 + ar + 32) * K + (K0) + ac8];   \
        ra2 = *(const bf16x8*)&Aq[(size_t)(row0 + ar + 64) * K + (K0) + ac8];   \
        ra3 = *(const bf16x8*)&Aq[(size_t)(row0 + ar + 96) * K + (K0) + ac8];   \
        rb0 = *(const bf16x8*)&Wq[(size_t)(col0 + ar) * K + (K0) + ac8];        \
        rb1 = *(const bf16x8*)&Wq[(size_t)(col0 + ar + 32) * K + (K0) + ac8];
        LOADGQ(0)
        for (int k0 = 0; k0 < K; k0 += 64) {
            __syncthreads();
            *(bf16x8*)&As[ar][ac8] = ra0;
            *(bf16x8*)&As[ar + 32][ac8] = ra1;
            *(bf16x8*)&As[ar + 64][ac8] = ra2;
            *(bf16x8*)&As[ar + 96][ac8] = ra3;
            *(bf16x8*)&Bs[ar][ac8] = rb0;
            *(bf16x8*)&Bs[ar + 32][ac8] = rb1;
            __syncthreads();
            if (k0 + 64 < K) { LOADGQ(k0 + 64) }
#pragma unroll
            for (int kk = 0; kk < 2; ++kk) {
                bf16x8 bfr[2];
#pragma unroll
                for (int ni = 0; ni < 2; ++ni) {
                    bf16x4 lo = *(const bf16x4*)&Bs[wc * 32 + ni * 16 + ln][kk * 32 + lg * 4];
                    bf16x4 hi = *(const bf16x4*)&Bs[wc * 32 + ni * 16 + ln][kk * 32 + 16 + lg * 4];
                    bfr[ni] = __builtin_shufflevector(lo, hi, 0, 1, 2, 3, 4, 5, 6, 7);
                }
#pragma unroll
                for (int mi = 0; mi < 4; ++mi) {
                    bf16x4 lo = *(const bf16x4*)&As[wr * 64 + mi * 16 + ln][kk * 32 + lg * 4];
                    bf16x4 hi = *(const bf16x4*)&As[wr * 64 + mi * 16 + ln][kk * 32 + 16 + lg * 4];
                    bf16x8 af = __builtin_shufflevector(lo, hi, 0, 1, 2, 3, 4, 5, 6, 7);
#pragma unroll
                    for (int ni = 0; ni < 2; ++ni)
                        acc[mi][ni] = __builtin_amdgcn_mfma_f32_16x16x32_bf16(bfr[ni], af, acc[mi][ni], 0, 0, 0);
                }
            }
        }
#undef LOADGQ
#pragma unroll
        for (int mi = 0; mi < 4; ++mi)
#pragma unroll
            for (int ni = 0; ni < 2; ++ni) {
                int cb = col0 + wc * 32 + ni * 16 + 4 * lg;
                float4 b4 = *(const float4*)&bq[cb];
                size_t row = row0 + wr * 64 + mi * 16 + ln;
                bf16x4 pk;
                pk[0] = (__bf16)((acc[mi][ni][0] + b4.x) * qscale);
                pk[1] = (__bf16)((acc[mi][ni][1] + b4.y) * qscale);
                pk[2] = (__bf16)((acc[mi][ni][2] + b4.z) * qscale);
                pk[3] = (__bf16)((acc[mi][ni][3] + b4.w) * qscale);
                *(bf16x4*)&Qo[row * DM + cb] = pk;
            }
    } else {
        // ---------------- K/V path (64-row tiles) ----------------
        f32x4v acc[2][2] = {};
        const int K = KVD;
        const int idx = blockIdx.x - 384;
        const int bx = idx & 7, row0 = (idx >> 3) * 64;
        const bool vpath = bx >= 4;
        const int col0 = (bx & 3) * 64;
        const __bf16* Wm = vpath ? Wv : Wk;
        const float* bi = vpath ? bv : bk;
        float4 a0, a1, a2, a3;
        bf16x8 rb0, rb1;
#define LOADGK(K0) \
        a0 = *(const float4*)&Yf[(size_t)(row0 + ar) * K + (K0) + ac8];            \
        a1 = *(const float4*)&Yf[(size_t)(row0 + ar) * K + (K0) + ac8 + 4];        \
        a2 = *(const float4*)&Yf[(size_t)(row0 + ar + 32) * K + (K0) + ac8];       \
        a3 = *(const float4*)&Yf[(size_t)(row0 + ar + 32) * K + (K0) + ac8 + 4];   \
        rb0 = *(const bf16x8*)&Wm[(size_t)(col0 + ar) * K + (K0) + ac8];           \
        rb1 = *(const bf16x8*)&Wm[(size_t)(col0 + ar + 32) * K + (K0) + ac8];
        LOADGK(0)
        for (int k0 = 0; k0 < K; k0 += 64) {
            __syncthreads();
            *(bf16x8*)&As[ar][ac8] = pack8(a0, a1);
            *(bf16x8*)&As[ar + 32][ac8] = pack8(a2, a3);
            *(bf16x8*)&Bs[ar][ac8] = rb0;
            *(bf16x8*)&Bs[ar + 32][ac8] = rb1;
            __syncthreads();
            if (k0 + 64 < K) { LOADGK(k0 + 64) }
#pragma unroll
            for (int kk = 0; kk < 2; ++kk) {
                bf16x8 bfr[2];
#pragma unroll
                for (int ni = 0; ni < 2; ++ni) {
                    bf16x4 lo = *(const bf16x4*)&Bs[wc * 32 + ni * 16 + ln][kk * 32 + lg * 4];
                    bf16x4 hi = *(const bf16x4*)&Bs[wc * 32 + ni * 16 + ln][kk * 32 + 16 + lg * 4];
                    bfr[ni] = __builtin_shufflevector(lo, hi, 0, 1, 2, 3, 4, 5, 6, 7);
                }
#pragma unroll
                for (int mi = 0; mi < 2; ++mi) {
                    bf16x4 lo = *(const bf16x4*)&As[wr * 32 + mi * 16 + ln][kk * 32 + lg * 4];
                    bf16x4 hi = *(const bf16x4*)&As[wr * 32 + mi * 16 + ln][kk * 32 + 16 + lg * 4];
                    bf16x8 af = __builtin_shufflevector(lo, hi, 0, 1, 2, 3, 4, 5, 6, 7);
#pragma unroll
                    for (int ni = 0; ni < 2; ++ni) {
                        if (vpath)
                            acc[mi][ni] = __builtin_amdgcn_mfma_f32_16x16x32_bf16(af, bfr[ni], acc[mi][ni], 0, 0, 0);
                        else
                            acc[mi][ni] = __builtin_amdgcn_mfma_f32_16x16x32_bf16(bfr[ni], af, acc[mi][ni], 0, 0, 0);
                    }
                }
            }
        }
#undef LOADGK
        if (vpath) {
            const int h = (col0 + wc * 32) >> 5;
#pragma unroll
            for (int mi = 0; mi < 2; ++mi)
#pragma unroll
                for (int ni = 0; ni < 2; ++ni) {
                    int C = col0 + wc * 32 + ni * 16 + ln;
                    int nt = (C >> 4) & 1;
                    float bvv = bi[C];
                    int m = row0 + wr * 32 + mi * 16 + 4 * lg;
                    int b = m >> 10, mlocal = m & 1023;
                    int mhg = mlocal >> 5;
                    bf16x4 pk;
#pragma unroll
                    for (int r = 0; r < 4; ++r) pk[r] = (__bf16)(acc[mi][ni][r] + bvv);
                    *(bf16x4*)&Vf[(size_t)(((b * NH + h) * 32 + mhg) * 2 + nt) * 512 + l * 8 + mi * 4] = pk;
                }
        } else {
            const int h = (col0 + wc * 32) >> 5;
#pragma unroll
            for (int mi = 0; mi < 2; ++mi) {
                int m = row0 + wr * 32 + mi * 16 + ln;
                int b = m >> 10, mlocal = m & 1023;
                int msg = mlocal >> 4;
#pragma unroll
                for (int ni = 0; ni < 2; ++ni) {
                    int cb = col0 + wc * 32 + ni * 16 + 4 * lg;
                    float4 b4 = *(const float4*)&bi[cb];
                    bf16x4 pk;
                    pk[0] = (__bf16)(acc[mi][ni][0] + b4.x);
                    pk[1] = (__bf16)(acc[mi][ni][1] + b4.y);
                    pk[2] = (__bf16)(acc[mi][ni][2] + b4.z);
                    pk[3] = (__bf16)(acc[mi][ni][3] + b4.w);
                    *(bf16x4*)&Kf[(size_t)((b * NH + h) * 64 + msg) * 512 + l * 8 + ni * 4] = pk;
                }
            }
        }
    }
}

// Flash cross-attention: ZERO LDS/barriers, fragment-layout K/V (L2-resident),
// NO-MAX exp2 softmax, MFMA-pipe denominator (Lacc = mfma(P, ones)).
// 128 q-rows per block: 2 Q frags/wave share every K/V fragment load.
__global__ __launch_bounds__(256) void k_attn_mfma(const __bf16* __restrict__ q,
        const __bf16* __restrict__ Kf, const __bf16* __restrict__ Vf,
        const int* __restrict__ starts, __bf16* __restrict__ o) {
    const int b = blockIdx.z, h = blockIdx.y;
    const int r0 = starts[b] + blockIdx.x * 128;
    const int rend = starts[b + 1];
    if (r0 >= rend) return;
    const int nr = min(128, rend - r0);

    const int t = threadIdx.x;
    const int w = t >> 6, l = t & 63, lg = l >> 4, ln = l & 15;

    const __bf16* kfb = Kf + (size_t)(b * NH + h) * 32768;
    const __bf16* vfb = Vf + (size_t)(b * NH + h) * 32768;

    const int qr0 = min(r0 + w * 32 + ln, NP - 1);
    const int qr1 = min(r0 + w * 32 + 16 + ln, NP - 1);
    const __bf16* qp0 = q + (size_t)qr0 * DM + h * DH;
    const __bf16* qp1 = q + (size_t)qr1 * DM + h * DH;
    bf16x8 qf0 = __builtin_shufflevector(*(const bf16x4*)(qp0 + lg * 4),
                                         *(const bf16x4*)(qp0 + 16 + lg * 4),
                                         0, 1, 2, 3, 4, 5, 6, 7);
    bf16x8 qf1 = __builtin_shufflevector(*(const bf16x4*)(qp1 + lg * 4),
                                         *(const bf16x4*)(qp1 + 16 + lg * 4),
                                         0, 1, 2, 3, 4, 5, 6, 7);

    bf16x8 onesf;
#pragma unroll
    for (int j = 0; j < 8; ++j) onesf[j] = (__bf16)1.0f;

    f32x4v OaccA[2] = {{0.f, 0.f, 0.f, 0.f}, {0.f, 0.f, 0.f, 0.f}};
    f32x4v OaccB[2] = {{0.f, 0.f, 0.f, 0.f}, {0.f, 0.f, 0.f, 0.f}};
    f32x4v LaccA = {0.f, 0.f, 0.f, 0.f};
    f32x4v LaccB = {0.f, 0.f, 0.f, 0.f};

    for (int mt = 0; mt < 8; ++mt) {
        bf16x8 kfr[8];
#pragma unroll
        for (int ms = 0; ms < 8; ++ms)
            kfr[ms] = *(const bf16x8*)&kfb[(size_t)((mt * 8 + ms) * 64 + l) * 8];
        f32x4v S0[8], S1[8];
        __builtin_amdgcn_s_setprio(1);
#pragma unroll
        for (int ms = 0; ms < 8; ++ms) {
            S0[ms] = __builtin_amdgcn_mfma_f32_16x16x32_bf16(
                kfr[ms], qf0, (f32x4v){0.f, 0.f, 0.f, 0.f}, 0, 0, 0);
            S1[ms] = __builtin_amdgcn_mfma_f32_16x16x32_bf16(
                kfr[ms], qf1, (f32x4v){0.f, 0.f, 0.f, 0.f}, 0, 0, 0);
        }
        __builtin_amdgcn_s_setprio(0);
        bf16x8 vfr[8];
#pragma unroll
        for (int i = 0; i < 8; ++i)
            vfr[i] = *(const bf16x8*)&vfb[(size_t)((mt * 8 + i) * 64 + l) * 8];
        // p = exp2(S), pack only (sums done on MFMA pipe below)
        bf16x8 pa0[4], pa1[4];
#pragma unroll
        for (int ms = 0; ms < 8; ++ms) {
            const int mh = ms >> 1, j0 = (ms & 1) * 4;
#pragma unroll
            for (int r = 0; r < 4; ++r)
                pa0[mh][j0 + r] = (__bf16)__builtin_amdgcn_exp2f(S0[ms][r]);
#pragma unroll
            for (int r = 0; r < 4; ++r)
                pa1[mh][j0 + r] = (__bf16)__builtin_amdgcn_exp2f(S1[ms][r]);
        }
        // PV + denominator-MFMA
        __builtin_amdgcn_s_setprio(1);
#pragma unroll
        for (int mh = 0; mh < 4; ++mh) {
#pragma unroll
            for (int nt = 0; nt < 2; ++nt) {
                OaccA[nt] = __builtin_amdgcn_mfma_f32_16x16x32_bf16(pa0[mh], vfr[mh * 2 + nt], OaccA[nt], 0, 0, 0);
                OaccB[nt] = __builtin_amdgcn_mfma_f32_16x16x32_bf16(pa1[mh], vfr[mh * 2 + nt], OaccB[nt], 0, 0, 0);
            }
            LaccA = __builtin_amdgcn_mfma_f32_16x16x32_bf16(pa0[mh], onesf, LaccA, 0, 0, 0);
            LaccB = __builtin_amdgcn_mfma_f32_16x16x32_bf16(pa1[mh], onesf, LaccB, 0, 0, 0);
        }
        __builtin_amdgcn_s_setprio(0);
    }
    // epilogue: Lacc[r] == row-sum for row 4lg+r (all lanes) -- no shuffles.
#pragma unroll
    for (int r = 0; r < 4; ++r) {
        float ivA = 1.0f / LaccA[r];
        float ivB = 1.0f / LaccB[r];
        int rlocA = w * 32 + 4 * lg + r;
        if (rlocA < nr) {
            size_t base = (size_t)(r0 + rlocA) * DM + h * DH + ln;
            o[base] = (__bf16)(OaccA[0][r] * ivA);
            o[base + 16] = (__bf16)(OaccA[1][r] * ivA);
        }
        int rlocB = w * 32 + 16 + 4 * lg + r;
        if (rlocB < nr) {
            size_t base = (size_t)(r0 + rlocB) * DM + h * DH + ln;
            o[base] = (__bf16)(OaccB[0][r] * ivB);
            o[base + 16] = (__bf16)(OaccB[1][r] * ivB);
        }
    }
}

// Wo projection + residual + final LayerNorm, fused. Tile 32 rows x 256 cols.
__global__ __launch_bounds__(256) void k_gemmo_ln(const __bf16* __restrict__ A,
        const __bf16* __restrict__ W, const float* __restrict__ bias,
        const __bf16* __restrict__ resid, const float* __restrict__ g,
        const float* __restrict__ bb, float* __restrict__ out) {
    __shared__ __bf16 As[32][68];
    __shared__ __bf16 Bs[256][68];
    __shared__ float red[32][4][2];
    const int t = threadIdx.x;
    const int w = t >> 6, l = t & 63, lg = l >> 4, ln = l & 15;
    const int row0 = blockIdx.x * 32;
    const int ar = t >> 3, ac8 = (t & 7) * 8;
    f32x4v acc[2][4] = {};
    for (int k0 = 0; k0 < DM; k0 += 64) {
        __syncthreads();
        *(bf16x8*)&As[ar][ac8] = *(const bf16x8*)&A[(size_t)(row0 + ar) * DM + k0 + ac8];
#pragma unroll
        for (int j = 0; j < 8; ++j)
            *(bf16x8*)&Bs[ar + 32 * j][ac8] = *(const bf16x8*)&W[(size_t)(ar + 32 * j) * DM + k0 + ac8];
        __syncthreads();
#pragma unroll
        for (int kk = 0; kk < 2; ++kk) {
            bf16x8 bfr[4];
#pragma unroll
            for (int ni = 0; ni < 4; ++ni) {
                bf16x4 lo = *(const bf16x4*)&Bs[w * 64 + ni * 16 + ln][kk * 32 + lg * 4];
                bf16x4 hi = *(const bf16x4*)&Bs[w * 64 + ni * 16 + ln][kk * 32 + 16 + lg * 4];
                bfr[ni] = __builtin_shufflevector(lo, hi, 0, 1, 2, 3, 4, 5, 6, 7);
            }
#pragma unroll
            for (int mi = 0; mi < 2; ++mi) {
                bf16x4 lo = *(const bf16x4*)&As[mi * 16 + ln][kk * 32 + lg * 4];
                bf16x4 hi = *(const bf16x4*)&As[mi * 16 + ln][kk * 32 + 16 + lg * 4];
                bf16x8 af = __builtin_shufflevector(lo, hi, 0, 1, 2, 3, 4, 5, 6, 7);
#pragma unroll
                for (int ni = 0; ni < 4; ++ni)
                    acc[mi][ni] = __builtin_amdgcn_mfma_f32_16x16x32_bf16(bfr[ni], af, acc[mi][ni], 0, 0, 0);
            }
        }
    }
    float s[2] = {0.f, 0.f}, ss[2] = {0.f, 0.f};
#pragma unroll
    for (int mi = 0; mi < 2; ++mi) {
        int row = row0 + mi * 16 + ln;
#pragma unroll
        for (int ni = 0; ni < 4; ++ni) {
            int cb = w * 64 + ni * 16 + lg * 4;
            float4 b4 = *(const float4*)&bias[cb];
            bf16x4 rv = *(const bf16x4*)&resid[(size_t)row * DM + cb];
            float z0 = acc[mi][ni][0] + b4.x + (float)rv[0];
            float z1 = acc[mi][ni][1] + b4.y + (float)rv[1];
            float z2 = acc[mi][ni][2] + b4.z + (float)rv[2];
            float z3 = acc[mi][ni][3] + b4.w + (float)rv[3];
            acc[mi][ni][0] = z0; acc[mi][ni][1] = z1;
            acc[mi][ni][2] = z2; acc[mi][ni][3] = z3;
            s[mi] += (z0 + z1) + (z2 + z3);
            ss[mi] += (z0 * z0 + z1 * z1) + (z2 * z2 + z3 * z3);
        }
    }
#pragma unroll
    for (int mi = 0; mi < 2; ++mi) {
        s[mi] += __shfl_xor(s[mi], 16);  s[mi] += __shfl_xor(s[mi], 32);
        ss[mi] += __shfl_xor(ss[mi], 16); ss[mi] += __shfl_xor(ss[mi], 32);
    }
    if (l < 16) {
#pragma unroll
        for (int mi = 0; mi < 2; ++mi) {
            red[mi * 16 + ln][w][0] = s[mi];
            red[mi * 16 + ln][w][1] = ss[mi];
        }
    }
    __syncthreads();
#pragma unroll
    for (int mi = 0; mi < 2; ++mi) {
        int rloc = mi * 16 + ln;
        float su = (red[rloc][0][0] + red[rloc][1][0]) + (red[rloc][2][0] + red[rloc][3][0]);
        float sq = (red[rloc][0][1] + red[rloc][1][1]) + (red[rloc][2][1] + red[rloc][3][1]);
        float mu = su * (1.f / DM);
        float var = sq * (1.f / DM) - mu * mu;
        float rs = rsqrtf(var + 1e-5f);
        size_t row = row0 + rloc;
#pragma unroll
        for (int ni = 0; ni < 4; ++ni) {
            int cb = w * 64 + ni * 16 + lg * 4;
            float4 g4 = *(const float4*)&g[cb];
            float4 bb4 = *(const float4*)&bb[cb];
            float4 o4;
            o4.x = (acc[mi][ni][0] - mu) * rs * g4.x + bb4.x;
            o4.y = (acc[mi][ni][1] - mu) * rs * g4.y + bb4.y;
            o4.z = (acc[mi][ni][2] - mu) * rs * g4.z + bb4.z;
            o4.w = (acc[mi][ni][3] - mu) * rs * g4.w + bb4.w;
            *(float4*)&out[row * DM + cb] = o4;
        }
    }
}

extern "C" void kernel_launch(void* const* d_in, const int* in_sizes, int n_in,
                              void* d_out, int out_size, void* d_ws, size_t ws_size,
                              hipStream_t stream) {
    const float* F  = (const float*)d_in[0];
    const int* bidx = (const int*)d_in[1];
    const float* y  = (const float*)d_in[2];
    const float* Wq = (const float*)d_in[3];
    const float* bq = (const float*)d_in[4];
    const float* Wk = (const float*)d_in[5];
    const float* bk = (const float*)d_in[6];
    const float* Wv = (const float*)d_in[7];
    const float* bv = (const float*)d_in[8];
    const float* Wo = (const float*)d_in[9];
    const float* bo = (const float*)d_in[10];
    const float* lg = (const float*)d_in[11];
    const float* lb = (const float*)d_in[12];
    float* out = (float*)d_out;

    char* ws = (char*)d_ws;
    __bf16* q_in_b = (__bf16*)ws;   ws += (size_t)NP * DM * 2;
    __bf16* qb     = (__bf16*)ws;   ws += (size_t)NP * DM * 2;
    __bf16* ob     = (__bf16*)ws;   ws += (size_t)NP * DM * 2;
    __bf16* Kf     = (__bf16*)ws;   ws += (size_t)NB * MC * DM * 2;
    __bf16* Vf     = (__bf16*)ws;   ws += (size_t)NB * DM * MC * 2;
    __bf16* Wq_b   = (__bf16*)ws;   ws += (size_t)DM * DM * 2;
    __bf16* Wk_b   = (__bf16*)ws;   ws += (size_t)DM * KVD * 2;
    __bf16* Wv_b   = (__bf16*)ws;   ws += (size_t)DM * KVD * 2;
    __bf16* Wo_b   = (__bf16*)ws;   ws += (size_t)DM * DM * 2;
    int* starts    = (int*)ws;

    const float qscale = 0.17677669529663687f * 1.4426950408889634f; // 1/sqrt(32)*log2e

    k_prep<<<1 + 384 + NP / 4, 256, 0, stream>>>(F, bidx, Wq, Wk, Wv, Wo, lg, lb,
            starts, Wq_b, Wk_b, Wv_b, Wo_b, q_in_b);
    k_qkv<<<384 + 512, 256, 0, stream>>>(q_in_b, Wq_b, bq, y, Wk_b, bk, Wv_b, bv,
            qb, Kf, Vf, qscale);
    k_attn_mfma<<<dim3(NP / 128, NH, NB), 256, 0, stream>>>(qb, Kf, Vf, starts, ob);
    k_gemmo_ln<<<NP / 32, 256, 0, stream>>>(ob, Wo_b, bo, q_in_b, lg, lb, out);
}

// Round 20
// 69.564 us; speedup vs baseline: 1.0821x; 1.0101x over previous
//
#include <hip/hip_runtime.h>

constexpr int NP = 12288;   // N points
constexpr int NB = 4;       // batches
constexpr int MC = 1024;    // M context
constexpr int DM = 256;     // D
constexpr int KVD = 512;    // KV feature dim
constexpr int NH = 8;       // heads
constexpr int DH = 32;      // head dim

typedef __bf16 bf16x8 __attribute__((ext_vector_type(8)));
typedef __bf16 bf16x4 __attribute__((ext_vector_type(4)));
typedef float f32x4v __attribute__((ext_vector_type(4)));

__device__ inline bf16x8 pack8(float4 a, float4 b) {
    bf16x8 r;
    r[0] = (__bf16)a.x; r[1] = (__bf16)a.y; r[2] = (__bf16)a.z; r[3] = (__bf16)a.w;
    r[4] = (__bf16)b.x; r[5] = (__bf16)b.y; r[6] = (__bf16)b.z; r[7] = (__bf16)b.w;
    return r;
}

// Merged prep: block 0 -> starts; blocks [1,384] -> weight fp32->bf16;
// blocks [385, 385+3072) -> LN1 of F (bf16 out).
__global__ __launch_bounds__(256) void k_prep(const float* __restrict__ F,
        const int* __restrict__ bidx,
        const float* __restrict__ wq, const float* __restrict__ wk,
        const float* __restrict__ wv, const float* __restrict__ wo,
        const float* __restrict__ g, const float* __restrict__ bb,
        int* __restrict__ starts,
        __bf16* wqb, __bf16* wkb, __bf16* wvb, __bf16* wob,
        __bf16* __restrict__ q_in_b) {
    const int bid = blockIdx.x, t = threadIdx.x;
    if (bid == 0) {
        if (t > NB) return;
        int lo = 0, hi = NP;
        while (lo < hi) { int mid = (lo + hi) >> 1; if (bidx[mid] < t) lo = mid + 1; else hi = mid; }
        starts[t] = lo;
        return;
    }
    if (bid <= 384) {
        size_t i = ((size_t)(bid - 1) * 256 + t) * 4;
        const float* s; __bf16* d; size_t off;
        if      (i < 65536)  { s = wq; d = wqb; off = 0; }
        else if (i < 196608) { s = wk; d = wkb; off = 65536; }
        else if (i < 327680) { s = wv; d = wvb; off = 196608; }
        else                 { s = wo; d = wob; off = 327680; }
        size_t j = i - off;
        float4 v = *(const float4*)&s[j];
        bf16x4 o; o[0] = (__bf16)v.x; o[1] = (__bf16)v.y; o[2] = (__bf16)v.z; o[3] = (__bf16)v.w;
        *(bf16x4*)&d[j] = o;
        return;
    }
    // LN1: 4 rows per block, wave per row
    const int w = t >> 6, l = t & 63;
    size_t row = (size_t)(bid - 385) * 4 + w;
    float4 v = *(const float4*)&F[row * DM + l * 4];
    float s = v.x + v.y + v.z + v.w;
#pragma unroll
    for (int o2 = 1; o2 < 64; o2 <<= 1) s += __shfl_xor(s, o2);
    float mu = s * (1.f / DM);
    float4 d = {v.x - mu, v.y - mu, v.z - mu, v.w - mu};
    float ss = d.x * d.x + d.y * d.y + d.z * d.z + d.w * d.w;
#pragma unroll
    for (int o2 = 1; o2 < 64; o2 <<= 1) ss += __shfl_xor(ss, o2);
    float rr = rsqrtf(ss * (1.f / DM) + 1e-5f);
    float4 gg = *(const float4*)&g[l * 4];
    float4 bv = *(const float4*)&bb[l * 4];
    bf16x4 ob4;
    ob4[0] = (__bf16)(d.x * rr * gg.x + bv.x);
    ob4[1] = (__bf16)(d.y * rr * gg.y + bv.y);
    ob4[2] = (__bf16)(d.z * rr * gg.z + bv.z);
    ob4[3] = (__bf16)(d.w * rr * gg.w + bv.w);
    *(bf16x4*)&q_in_b[row * DM + l * 4] = ob4;
}

// Merged Q + K + V projections (fragment-layout K/V out).
__global__ __launch_bounds__(256) void k_qkv(const __bf16* __restrict__ Aq,
        const __bf16* __restrict__ Wq, const float* __restrict__ bq,
        const float* __restrict__ Yf,
        const __bf16* __restrict__ Wk, const float* __restrict__ bk,
        const __bf16* __restrict__ Wv, const float* __restrict__ bv,
        __bf16* __restrict__ Qo, __bf16* __restrict__ Kf,
        __bf16* __restrict__ Vf, float qscale) {
    __shared__ __bf16 As[128][68];
    __shared__ __bf16 Bs[64][68];
    const int t = threadIdx.x;
    const int w = t >> 6, l = t & 63, lg = l >> 4, ln = l & 15;
    const int wr = w >> 1, wc = w & 1;
    const int ar = t >> 3, ac8 = (t & 7) * 8;
    if ((int)blockIdx.x < 384) {
        // ---------------- Q path ----------------
        f32x4v acc[4][2] = {};
        const int K = DM;
        const int col0 = (blockIdx.x & 3) * 64, row0 = (blockIdx.x >> 2) * 128;
        bf16x8 ra0, ra1, ra2, ra3, rb0, rb1;
#define LOADGQ(K0) \
        ra0 = *(const bf16x8*)&Aq[(size_t)(row0 + ar) * K + (K0) + ac8];        \
        ra1 = *(const bf16x8*)&Aq[(size_t)(row0 + ar + 32) * K + (K0) + ac8];   \
        ra2 = *(const bf16x8*)&Aq[(size_t)(row0 + ar + 64) * K + (K0) + ac8];   \
        ra3 = *(const bf16x8*)&Aq[(size_t)(row0 + ar + 96) * K + (K0) + ac8];   \
        rb0 = *(const bf16x8*)&Wq[(size_t)(col0 + ar) * K + (K0) + ac8];        \
        rb1 = *(const bf16x8*)&Wq[(size_t)(col0 + ar + 32) * K + (K0) + ac8];
        LOADGQ(0)
        for (int k0 = 0; k0 < K; k0 += 64) {
            __syncthreads();
            *(bf16x8*)&As[ar][ac8] = ra0;
            *(bf16x8*)&As[ar + 32][ac8] = ra1;
            *(bf16x8*)&As[ar + 64][ac8] = ra2;
            *(bf16x8*)&As[ar + 96][ac8] = ra3;
            *(bf16x8*)&Bs[ar][ac8] = rb0;
            *(bf16x8*)&Bs[ar + 32][ac8] = rb1;
            __syncthreads();
            if (k0 + 64 < K) { LOADGQ(k0 + 64) }
#pragma unroll
            for (int kk = 0; kk < 2; ++kk) {
                bf16x8 bfr[2];
#pragma unroll
                for (int ni = 0; ni < 2; ++ni) {
                    bf16x4 lo = *(const bf16x4*)&Bs[wc * 32 + ni * 16 + ln][kk * 32 + lg * 4];
                    bf16x4 hi = *(const bf16x4*)&Bs[wc * 32 + ni * 16 + ln][kk * 32 + 16 + lg * 4];
                    bfr[ni] = __builtin_shufflevector(lo, hi, 0, 1, 2, 3, 4, 5, 6, 7);
                }
#pragma unroll
                for (int mi = 0; mi < 4; ++mi) {
                    bf16x4 lo = *(const bf16x4*)&As[wr * 64 + mi * 16 + ln][kk * 32 + lg * 4];
                    bf16x4 hi = *(const bf16x4*)&As[wr * 64 + mi * 16 + ln][kk * 32 + 16 + lg * 4];
                    bf16x8 af = __builtin_shufflevector(lo, hi, 0, 1, 2, 3, 4, 5, 6, 7);
#pragma unroll
                    for (int ni = 0; ni < 2; ++ni)
                        acc[mi][ni] = __builtin_amdgcn_mfma_f32_16x16x32_bf16(bfr[ni], af, acc[mi][ni], 0, 0, 0);
                }
            }
        }
#undef LOADGQ
#pragma unroll
        for (int mi = 0; mi < 4; ++mi)
#pragma unroll
            for (int ni = 0; ni < 2; ++ni) {
                int cb = col0 + wc * 32 + ni * 16 + 4 * lg;
                float4 b4 = *(const float4*)&bq[cb];
                size_t row = row0 + wr * 64 + mi * 16 + ln;
                bf16x4 pk;
                pk[0] = (__bf16)((acc[mi][ni][0] + b4.x) * qscale);
                pk[1] = (__bf16)((acc[mi][ni][1] + b4.y) * qscale);
                pk[2] = (__bf16)((acc[mi][ni][2] + b4.z) * qscale);
                pk[3] = (__bf16)((acc[mi][ni][3] + b4.w) * qscale);
                *(bf16x4*)&Qo[row * DM + cb] = pk;
            }
    } else {
        // ---------------- K/V path (64-row tiles) ----------------
        f32x4v acc[2][2] = {};
        const int K = KVD;
        const int idx = blockIdx.x - 384;
        const int bx = idx & 7, row0 = (idx >> 3) * 64;
        const bool vpath = bx >= 4;
        const int col0 = (bx & 3) * 64;
        const __bf16* Wm = vpath ? Wv : Wk;
        const float* bi = vpath ? bv : bk;
        float4 a0, a1, a2, a3;
        bf16x8 rb0, rb1;
#define LOADGK(K0) \
        a0 = *(const float4*)&Yf[(size_t)(row0 + ar) * K + (K0) + ac8];            \
        a1 = *(const float4*)&Yf[(size_t)(row0 + ar) * K + (K0) + ac8 + 4];        \
        a2 = *(const float4*)&Yf[(size_t)(row0 + ar + 32) * K + (K0) + ac8];       \
        a3 = *(const float4*)&Yf[(size_t)(row0 + ar + 32) * K + (K0) + ac8 + 4];   \
        rb0 = *(const bf16x8*)&Wm[(size_t)(col0 + ar) * K + (K0) + ac8];           \
        rb1 = *(const bf16x8*)&Wm[(size_t)(col0 + ar + 32) * K + (K0) + ac8];
        LOADGK(0)
        for (int k0 = 0; k0 < K; k0 += 64) {
            __syncthreads();
            *(bf16x8*)&As[ar][ac8] = pack8(a0, a1);
            *(bf16x8*)&As[ar + 32][ac8] = pack8(a2, a3);
            *(bf16x8*)&Bs[ar][ac8] = rb0;
            *(bf16x8*)&Bs[ar + 32][ac8] = rb1;
            __syncthreads();
            if (k0 + 64 < K) { LOADGK(k0 + 64) }
#pragma unroll
            for (int kk = 0; kk < 2; ++kk) {
                bf16x8 bfr[2];
#pragma unroll
                for (int ni = 0; ni < 2; ++ni) {
                    bf16x4 lo = *(const bf16x4*)&Bs[wc * 32 + ni * 16 + ln][kk * 32 + lg * 4];
                    bf16x4 hi = *(const bf16x4*)&Bs[wc * 32 + ni * 16 + ln][kk * 32 + 16 + lg * 4];
                    bfr[ni] = __builtin_shufflevector(lo, hi, 0, 1, 2, 3, 4, 5, 6, 7);
                }
#pragma unroll
                for (int mi = 0; mi < 2; ++mi) {
                    bf16x4 lo = *(const bf16x4*)&As[wr * 32 + mi * 16 + ln][kk * 32 + lg * 4];
                    bf16x4 hi = *(const bf16x4*)&As[wr * 32 + mi * 16 + ln][kk * 32 + 16 + lg * 4];
                    bf16x8 af = __builtin_shufflevector(lo, hi, 0, 1, 2, 3, 4, 5, 6, 7);
#pragma unroll
                    for (int ni = 0; ni < 2; ++ni) {
                        if (vpath)
                            acc[mi][ni] = __builtin_amdgcn_mfma_f32_16x16x32_bf16(af, bfr[ni], acc[mi][ni], 0, 0, 0);
                        else
                            acc[mi][ni] = __builtin_amdgcn_mfma_f32_16x16x32_bf16(bfr[ni], af, acc[mi][ni], 0, 0, 0);
                    }
                }
            }
        }
#undef LOADGK
        if (vpath) {
            const int h = (col0 + wc * 32) >> 5;
#pragma unroll
            for (int mi = 0; mi < 2; ++mi)
#pragma unroll
                for (int ni = 0; ni < 2; ++ni) {
                    int C = col0 + wc * 32 + ni * 16 + ln;
                    int nt = (C >> 4) & 1;
                    float bvv = bi[C];
                    int m = row0 + wr * 32 + mi * 16 + 4 * lg;
                    int b = m >> 10, mlocal = m & 1023;
                    int mhg = mlocal >> 5;
                    bf16x4 pk;
#pragma unroll
                    for (int r = 0; r < 4; ++r) pk[r] = (__bf16)(acc[mi][ni][r] + bvv);
                    *(bf16x4*)&Vf[(size_t)(((b * NH + h) * 32 + mhg) * 2 + nt) * 512 + l * 8 + mi * 4] = pk;
                }
        } else {
            const int h = (col0 + wc * 32) >> 5;
#pragma unroll
            for (int mi = 0; mi < 2; ++mi) {
                int m = row0 + wr * 32 + mi * 16 + ln;
                int b = m >> 10, mlocal = m & 1023;
                int msg = mlocal >> 4;
#pragma unroll
                for (int ni = 0; ni < 2; ++ni) {
                    int cb = col0 + wc * 32 + ni * 16 + 4 * lg;
                    float4 b4 = *(const float4*)&bi[cb];
                    bf16x4 pk;
                    pk[0] = (__bf16)(acc[mi][ni][0] + b4.x);
                    pk[1] = (__bf16)(acc[mi][ni][1] + b4.y);
                    pk[2] = (__bf16)(acc[mi][ni][2] + b4.z);
                    pk[3] = (__bf16)(acc[mi][ni][3] + b4.w);
                    *(bf16x4*)&Kf[(size_t)((b * NH + h) * 64 + msg) * 512 + l * 8 + ni * 4] = pk;
                }
            }
        }
    }
}

// Flash cross-attention: ZERO LDS/barriers, fragment-layout K/V, NO-MAX exp2
// softmax, MFMA-pipe denominator, 128 q-rows per block (2 Q frags/wave).
// NEW: 1D grid (3072 blocks) + bijective XCD swizzle: wg = (orig&7)*384 +
// orig>>3 gives each XCD a contiguous 384-wgid chunk = 4 (b,h) K/V slices
// (512 KB) -> all consumers of a slice share one XCD's L2 (was spread over 8).
__global__ __launch_bounds__(256) void k_attn_mfma(const __bf16* __restrict__ q,
        const __bf16* __restrict__ Kf, const __bf16* __restrict__ Vf,
        const int* __restrict__ starts, __bf16* __restrict__ o) {
    const int orig = blockIdx.x;
    const int wg = (orig & 7) * 384 + (orig >> 3);   // bijective: 3072 = 8*384
    const int x = wg % 96;
    const int hb = wg / 96;
    const int h = hb & 7, b = hb >> 3;
    const int r0 = starts[b] + x * 128;
    const int rend = starts[b + 1];
    if (r0 >= rend) return;
    const int nr = min(128, rend - r0);

    const int t = threadIdx.x;
    const int w = t >> 6, l = t & 63, lg = l >> 4, ln = l & 15;

    const __bf16* kfb = Kf + (size_t)(b * NH + h) * 32768;
    const __bf16* vfb = Vf + (size_t)(b * NH + h) * 32768;

    const int qr0 = min(r0 + w * 32 + ln, NP - 1);
    const int qr1 = min(r0 + w * 32 + 16 + ln, NP - 1);
    const __bf16* qp0 = q + (size_t)qr0 * DM + h * DH;
    const __bf16* qp1 = q + (size_t)qr1 * DM + h * DH;
    bf16x8 qf0 = __builtin_shufflevector(*(const bf16x4*)(qp0 + lg * 4),
                                         *(const bf16x4*)(qp0 + 16 + lg * 4),
                                         0, 1, 2, 3, 4, 5, 6, 7);
    bf16x8 qf1 = __builtin_shufflevector(*(const bf16x4*)(qp1 + lg * 4),
                                         *(const bf16x4*)(qp1 + 16 + lg * 4),
                                         0, 1, 2, 3, 4, 5, 6, 7);

    bf16x8 onesf;
#pragma unroll
    for (int j = 0; j < 8; ++j) onesf[j] = (__bf16)1.0f;

    f32x4v OaccA[2] = {{0.f, 0.f, 0.f, 0.f}, {0.f, 0.f, 0.f, 0.f}};
    f32x4v OaccB[2] = {{0.f, 0.f, 0.f, 0.f}, {0.f, 0.f, 0.f, 0.f}};
    f32x4v LaccA = {0.f, 0.f, 0.f, 0.f};
    f32x4v LaccB = {0.f, 0.f, 0.f, 0.f};

    for (int mt = 0; mt < 8; ++mt) {
        bf16x8 kfr[8];
#pragma unroll
        for (int ms = 0; ms < 8; ++ms)
            kfr[ms] = *(const bf16x8*)&kfb[(size_t)((mt * 8 + ms) * 64 + l) * 8];
        f32x4v S0[8], S1[8];
        __builtin_amdgcn_s_setprio(1);
#pragma unroll
        for (int ms = 0; ms < 8; ++ms) {
            S0[ms] = __builtin_amdgcn_mfma_f32_16x16x32_bf16(
                kfr[ms], qf0, (f32x4v){0.f, 0.f, 0.f, 0.f}, 0, 0, 0);
            S1[ms] = __builtin_amdgcn_mfma_f32_16x16x32_bf16(
                kfr[ms], qf1, (f32x4v){0.f, 0.f, 0.f, 0.f}, 0, 0, 0);
        }
        __builtin_amdgcn_s_setprio(0);
        bf16x8 vfr[8];
#pragma unroll
        for (int i = 0; i < 8; ++i)
            vfr[i] = *(const bf16x8*)&vfb[(size_t)((mt * 8 + i) * 64 + l) * 8];
        // p = exp2(S), pack only (sums done on MFMA pipe below)
        bf16x8 pa0[4], pa1[4];
#pragma unroll
        for (int ms = 0; ms < 8; ++ms) {
            const int mh = ms >> 1, j0 = (ms & 1) * 4;
#pragma unroll
            for (int r = 0; r < 4; ++r)
                pa0[mh][j0 + r] = (__bf16)__builtin_amdgcn_exp2f(S0[ms][r]);
#pragma unroll
            for (int r = 0; r < 4; ++r)
                pa1[mh][j0 + r] = (__bf16)__builtin_amdgcn_exp2f(S1[ms][r]);
        }
        // PV + denominator-MFMA
        __builtin_amdgcn_s_setprio(1);
#pragma unroll
        for (int mh = 0; mh < 4; ++mh) {
#pragma unroll
            for (int nt = 0; nt < 2; ++nt) {
                OaccA[nt] = __builtin_amdgcn_mfma_f32_16x16x32_bf16(pa0[mh], vfr[mh * 2 + nt], OaccA[nt], 0, 0, 0);
                OaccB[nt] = __builtin_amdgcn_mfma_f32_16x16x32_bf16(pa1[mh], vfr[mh * 2 + nt], OaccB[nt], 0, 0, 0);
            }
            LaccA = __builtin_amdgcn_mfma_f32_16x16x32_bf16(pa0[mh], onesf, LaccA, 0, 0, 0);
            LaccB = __builtin_amdgcn_mfma_f32_16x16x32_bf16(pa1[mh], onesf, LaccB, 0, 0, 0);
        }
        __builtin_amdgcn_s_setprio(0);
    }
    // epilogue: Lacc[r] == row-sum for row 4lg+r (all lanes) -- no shuffles.
#pragma unroll
    for (int r = 0; r < 4; ++r) {
        float ivA = 1.0f / LaccA[r];
        float ivB = 1.0f / LaccB[r];
        int rlocA = w * 32 + 4 * lg + r;
        if (rlocA < nr) {
            size_t base = (size_t)(r0 + rlocA) * DM + h * DH + ln;
            o[base] = (__bf16)(OaccA[0][r] * ivA);
            o[base + 16] = (__bf16)(OaccA[1][r] * ivA);
        }
        int rlocB = w * 32 + 16 + 4 * lg + r;
        if (rlocB < nr) {
            size_t base = (size_t)(r0 + rlocB) * DM + h * DH + ln;
            o[base] = (__bf16)(OaccB[0][r] * ivB);
            o[base + 16] = (__bf16)(OaccB[1][r] * ivB);
        }
    }
}

// Wo projection + residual + final LayerNorm, fused. Tile 32 rows x 256 cols.
__global__ __launch_bounds__(256) void k_gemmo_ln(const __bf16* __restrict__ A,
        const __bf16* __restrict__ W, const float* __restrict__ bias,
        const __bf16* __restrict__ resid, const float* __restrict__ g,
        const float* __restrict__ bb, float* __restrict__ out) {
    __shared__ __bf16 As[32][68];
    __shared__ __bf16 Bs[256][68];
    __shared__ float red[32][4][2];
    const int t = threadIdx.x;
    const int w = t >> 6, l = t & 63, lg = l >> 4, ln = l & 15;
    const int row0 = blockIdx.x * 32;
    const int ar = t >> 3, ac8 = (t & 7) * 8;
    f32x4v acc[2][4] = {};
    for (int k0 = 0; k0 < DM; k0 += 64) {
        __syncthreads();
        *(bf16x8*)&As[ar][ac8] = *(const bf16x8*)&A[(size_t)(row0 + ar) * DM + k0 + ac8];
#pragma unroll
        for (int j = 0; j < 8; ++j)
            *(bf16x8*)&Bs[ar + 32 * j][ac8] = *(const bf16x8*)&W[(size_t)(ar + 32 * j) * DM + k0 + ac8];
        __syncthreads();
#pragma unroll
        for (int kk = 0; kk < 2; ++kk) {
            bf16x8 bfr[4];
#pragma unroll
            for (int ni = 0; ni < 4; ++ni) {
                bf16x4 lo = *(const bf16x4*)&Bs[w * 64 + ni * 16 + ln][kk * 32 + lg * 4];
                bf16x4 hi = *(const bf16x4*)&Bs[w * 64 + ni * 16 + ln][kk * 32 + 16 + lg * 4];
                bfr[ni] = __builtin_shufflevector(lo, hi, 0, 1, 2, 3, 4, 5, 6, 7);
            }
#pragma unroll
            for (int mi = 0; mi < 2; ++mi) {
                bf16x4 lo = *(const bf16x4*)&As[mi * 16 + ln][kk * 32 + lg * 4];
                bf16x4 hi = *(const bf16x4*)&As[mi * 16 + ln][kk * 32 + 16 + lg * 4];
                bf16x8 af = __builtin_shufflevector(lo, hi, 0, 1, 2, 3, 4, 5, 6, 7);
#pragma unroll
                for (int ni = 0; ni < 4; ++ni)
                    acc[mi][ni] = __builtin_amdgcn_mfma_f32_16x16x32_bf16(bfr[ni], af, acc[mi][ni], 0, 0, 0);
            }
        }
    }
    float s[2] = {0.f, 0.f}, ss[2] = {0.f, 0.f};
#pragma unroll
    for (int mi = 0; mi < 2; ++mi) {
        int row = row0 + mi * 16 + ln;
#pragma unroll
        for (int ni = 0; ni < 4; ++ni) {
            int cb = w * 64 + ni * 16 + lg * 4;
            float4 b4 = *(const float4*)&bias[cb];
            bf16x4 rv = *(const bf16x4*)&resid[(size_t)row * DM + cb];
            float z0 = acc[mi][ni][0] + b4.x + (float)rv[0];
            float z1 = acc[mi][ni][1] + b4.y + (float)rv[1];
            float z2 = acc[mi][ni][2] + b4.z + (float)rv[2];
            float z3 = acc[mi][ni][3] + b4.w + (float)rv[3];
            acc[mi][ni][0] = z0; acc[mi][ni][1] = z1;
            acc[mi][ni][2] = z2; acc[mi][ni][3] = z3;
            s[mi] += (z0 + z1) + (z2 + z3);
            ss[mi] += (z0 * z0 + z1 * z1) + (z2 * z2 + z3 * z3);
        }
    }
#pragma unroll
    for (int mi = 0; mi < 2; ++mi) {
        s[mi] += __shfl_xor(s[mi], 16);  s[mi] += __shfl_xor(s[mi], 32);
        ss[mi] += __shfl_xor(ss[mi], 16); ss[mi] += __shfl_xor(ss[mi], 32);
    }
    if (l < 16) {
#pragma unroll
        for (int mi = 0; mi < 2; ++mi) {
            red[mi * 16 + ln][w][0] = s[mi];
            red[mi * 16 + ln][w][1] = ss[mi];
        }
    }
    __syncthreads();
#pragma unroll
    for (int mi = 0; mi < 2; ++mi) {
        int rloc = mi * 16 + ln;
        float su = (red[rloc][0][0] + red[rloc][1][0]) + (red[rloc][2][0] + red[rloc][3][0]);
        float sq = (red[rloc][0][1] + red[rloc][1][1]) + (red[rloc][2][1] + red[rloc][3][1]);
        float mu = su * (1.f / DM);
        float var = sq * (1.f / DM) - mu * mu;
        float rs = rsqrtf(var + 1e-5f);
        size_t row = row0 + rloc;
#pragma unroll
        for (int ni = 0; ni < 4; ++ni) {
            int cb = w * 64 + ni * 16 + lg * 4;
            float4 g4 = *(const float4*)&g[cb];
            float4 bb4 = *(const float4*)&bb[cb];
            float4 o4;
            o4.x = (acc[mi][ni][0] - mu) * rs * g4.x + bb4.x;
            o4.y = (acc[mi][ni][1] - mu) * rs * g4.y + bb4.y;
            o4.z = (acc[mi][ni][2] - mu) * rs * g4.z + bb4.z;
            o4.w = (acc[mi][ni][3] - mu) * rs * g4.w + bb4.w;
            *(float4*)&out[row * DM + cb] = o4;
        }
    }
}

extern "C" void kernel_launch(void* const* d_in, const int* in_sizes, int n_in,
                              void* d_out, int out_size, void* d_ws, size_t ws_size,
                              hipStream_t stream) {
    const float* F  = (const float*)d_in[0];
    const int* bidx = (const int*)d_in[1];
    const float* y  = (const float*)d_in[2];
    const float* Wq = (const float*)d_in[3];
    const float* bq = (const float*)d_in[4];
    const float* Wk = (const float*)d_in[5];
    const float* bk = (const float*)d_in[6];
    const float* Wv = (const float*)d_in[7];
    const float* bv = (const float*)d_in[8];
    const float* Wo = (const float*)d_in[9];
    const float* bo = (const float*)d_in[10];
    const float* lg = (const float*)d_in[11];
    const float* lb = (const float*)d_in[12];
    float* out = (float*)d_out;

    char* ws = (char*)d_ws;
    __bf16* q_in_b = (__bf16*)ws;   ws += (size_t)NP * DM * 2;
    __bf16* qb     = (__bf16*)ws;   ws += (size_t)NP * DM * 2;
    __bf16* ob     = (__bf16*)ws;   ws += (size_t)NP * DM * 2;
    __bf16* Kf     = (__bf16*)ws;   ws += (size_t)NB * MC * DM * 2;
    __bf16* Vf     = (__bf16*)ws;   ws += (size_t)NB * DM * MC * 2;
    __bf16* Wq_b   = (__bf16*)ws;   ws += (size_t)DM * DM * 2;
    __bf16* Wk_b   = (__bf16*)ws;   ws += (size_t)DM * KVD * 2;
    __bf16* Wv_b   = (__bf16*)ws;   ws += (size_t)DM * KVD * 2;
    __bf16* Wo_b   = (__bf16*)ws;   ws += (size_t)DM * DM * 2;
    int* starts    = (int*)ws;

    const float qscale = 0.17677669529663687f * 1.4426950408889634f; // 1/sqrt(32)*log2e

    k_prep<<<1 + 384 + NP / 4, 256, 0, stream>>>(F, bidx, Wq, Wk, Wv, Wo, lg, lb,
            starts, Wq_b, Wk_b, Wv_b, Wo_b, q_in_b);
    k_qkv<<<384 + 512, 256, 0, stream>>>(q_in_b, Wq_b, bq, y, Wk_b, bk, Wv_b, bv,
            qb, Kf, Vf, qscale);
    k_attn_mfma<<<3072, 256, 0, stream>>>(qb, Kf, Vf, starts, ob);
    k_gemmo_ln<<<NP / 32, 256, 0, stream>>>(ob, Wo_b, bo, q_in_b, lg, lb, out);
}